// Round 8
// baseline (315.845 us; speedup 1.0000x reference)
//
#include <hip/hip_runtime.h>
#include <hip/hip_bf16.h>

#define N_PIX 2304
#define C_IN  256
#define INNER 384
#define HEADS 8
#define HDIM  48
#define DPAD  64
// attention scale folded with log2(e): softmax runs in exp2 domain
#define QSCALE (0.14433756729740643f * 1.44269504088896341f)

typedef __bf16 bf16x8 __attribute__((ext_vector_type(8)));
typedef float  f32x4  __attribute__((ext_vector_type(4)));
typedef short  s16x8  __attribute__((ext_vector_type(8)));

union Frag { s16x8 s; bf16x8 b; uint2 u[2]; };

__device__ inline short f2bf_bits(float f){
  union { float f; unsigned u; } v; v.f = f;
  unsigned r = v.u + 0x7fffu + ((v.u >> 16) & 1u);
  return (short)(r >> 16);
}

__device__ inline unsigned cvt_pk(float a, float b){
  unsigned r; asm("v_cvt_pk_bf16_f32 %0, %1, %2" : "=v"(r) : "v"(a), "v"(b));
  return r;
}

// ---------- fused: GroupNorm stats (blocks 0..127) + weight f32->bf16 (blocks 128..319) ----------
__global__ __launch_bounds__(256) void gn_wconv(const float* __restrict__ x,
                                                float* __restrict__ mu, float* __restrict__ rs,
                                                const float* __restrict__ wa, const float* __restrict__ wb,
                                                const float* __restrict__ wc, const float* __restrict__ wd,
                                                short* __restrict__ dst){
  __shared__ float ls[256], ls2[256];
  if (blockIdx.x < 128){
    int bg = blockIdx.x;
    const float* p = x + (size_t)bg * 8 * N_PIX;
    float s = 0.f, s2 = 0.f;
    for (int i = threadIdx.x; i < 8 * N_PIX; i += 256){
      float v = p[i]; s += v; s2 += v * v;
    }
    ls[threadIdx.x] = s; ls2[threadIdx.x] = s2;
    __syncthreads();
    for (int off = 128; off > 0; off >>= 1){
      if ((int)threadIdx.x < off){ ls[threadIdx.x] += ls[threadIdx.x + off]; ls2[threadIdx.x] += ls2[threadIdx.x + off]; }
      __syncthreads();
    }
    if (threadIdx.x == 0){
      float m = ls[0] / 18432.f;
      float var = ls2[0] / 18432.f - m * m;
      mu[bg] = m; rs[bg] = rsqrtf(var + 1e-5f);
    }
  } else {
    int i = ((blockIdx.x - 128) * 256 + threadIdx.x) * 8;   // 192 blocks * 2048 = 393216
    const float* src;
    if (i < 98304) src = wa + i;
    else if (i < 196608) src = wb + (i - 98304);
    else if (i < 294912) src = wc + (i - 196608);
    else src = wd + (i - 294912);
    float4 v0 = *(const float4*)src;
    float4 v1 = *(const float4*)(src + 4);
    uint4 o;
    o.x = cvt_pk(v0.x, v0.y); o.y = cvt_pk(v0.z, v0.w);
    o.z = cvt_pk(v1.x, v1.y); o.w = cvt_pk(v1.z, v1.w);
    *(uint4*)(dst + i) = o;
  }
}

// ------- transpose [b,c,n] f32 -> [b,n,c] bf16, GN folded for q (which==0) -------
__global__ __launch_bounds__(256) void prep_x(const float* __restrict__ Xq, const float* __restrict__ Xkv,
                                              const float* __restrict__ gnw, const float* __restrict__ gnb,
                                              const float* __restrict__ mu, const float* __restrict__ rs,
                                              short* __restrict__ XTq, short* __restrict__ XTkv){
  int which = blockIdx.z >> 2;
  int b = blockIdx.z & 3;
  int nb = blockIdx.x * 64, cb = blockIdx.y * 64;
  const float* X = which ? Xkv : Xq;
  short* XT = which ? XTkv : XTq;
  __shared__ __align__(16) short lt[64][68];
  int t = threadIdx.x;
  int c_l = t >> 4, n4 = (t & 15) * 4;
  #pragma unroll
  for (int i = 0; i < 4; ++i){
    int cl = c_l + i * 16, c = cb + cl;
    float4 v = *(const float4*)(X + ((size_t)b * C_IN + c) * N_PIX + nb + n4);
    if (which == 0){
      int bg = b * 32 + (c >> 3);
      float w = gnw[c] * rs[bg], bb = gnb[c] - mu[bg] * w;
      v.x = v.x * w + bb; v.y = v.y * w + bb; v.z = v.z * w + bb; v.w = v.w * w + bb;
    }
    uint2 p; p.x = cvt_pk(v.x, v.y); p.y = cvt_pk(v.z, v.w);
    *(uint2*)&lt[cl][n4] = p;
  }
  __syncthreads();
  #pragma unroll
  for (int i = 0; i < 2; ++i){
    int idx = t + i * 256;
    int n = idx >> 3, c8 = (idx & 7) * 8;
    s16x8 o;
    #pragma unroll
    for (int j = 0; j < 8; ++j) o[j] = lt[c8 + j][n];
    *(s16x8*)(XT + ((size_t)b * N_PIX + nb + n) * C_IN + cb + c8) = o;
  }
}

// ---- fused Q/K/V projection. y/6: 0=Q (GN'd input, scaled, padded), 1=K, 2=V (transposed out) ----
__global__ __launch_bounds__(256) void proj_qkv(const short* __restrict__ XTq,
                                                const short* __restrict__ XTkv,
                                                const short* __restrict__ WBF,
                                                const float* __restrict__ bq,
                                                const float* __restrict__ bk,
                                                const float* __restrict__ bv,
                                                short* __restrict__ QH,
                                                short* __restrict__ KH,
                                                short* __restrict__ VTB){
  int b = blockIdx.z, nb = blockIdx.x * 64;
  int y = blockIdx.y;
  int which = y / 6;                 // 0,1,2
  int ob = (y % 6) * 64;
  const short* XT = which ? XTkv : XTq;
  const short* WB = WBF + which * 98304;
  int wave = threadIdx.x >> 6, lane = threadIdx.x & 63;
  int l16 = lane & 15, lq = lane >> 4;
  int o0 = ob + wave * 16;

  f32x4 acc[4] = {};
  const short* xbase = XT + ((size_t)b * N_PIX + nb) * C_IN;
  #pragma unroll
  for (int k = 0; k < 8; ++k){
    Frag wf; wf.s = *(const s16x8*)(WB + (size_t)(o0 + l16) * C_IN + k * 32 + lq * 8);
    #pragma unroll
    for (int nt = 0; nt < 4; ++nt){
      Frag af; af.s = *(const s16x8*)(xbase + (size_t)(nt * 16 + l16) * C_IN + k * 32 + lq * 8);
      acc[nt] = (which == 2)
        ? __builtin_amdgcn_mfma_f32_16x16x32_bf16(wf.b, af.b, acc[nt], 0, 0, 0)   // D[o][n]
        : __builtin_amdgcn_mfma_f32_16x16x32_bf16(af.b, wf.b, acc[nt], 0, 0, 0);  // D[n][o]
  }
  }
  if (which == 2){                                   // V -> VT[b,h,d,n]
    #pragma unroll
    for (int r = 0; r < 4; ++r){
      int o = o0 + lq * 4 + r;
      int h = (o * 683) >> 15, d = o - h * 48;
      float bvv = bv[o];
      #pragma unroll
      for (int nt = 0; nt < 4; ++nt){
        int n = nb + nt * 16 + l16;
        VTB[(((size_t)b * HEADS + h) * DPAD + d) * N_PIX + n] = f2bf_bits(acc[nt][r] + bvv);
      }
    }
  } else {                                           // Q/K -> [b,h,n,64]
    short* OUT = which ? KH : QH;
    const float* bias = which ? bk : bq;
    float scale = which ? 1.0f : (float)QSCALE;
    int o = o0 + l16;
    int h = (o * 683) >> 15, d = o - h * 48;
    float bvv = bias[o];
    #pragma unroll
    for (int nt = 0; nt < 4; ++nt)
      #pragma unroll
      for (int r = 0; r < 4; ++r){
        int n = nb + nt * 16 + lq * 4 + r;
        OUT[(((size_t)b * HEADS + h) * N_PIX + n) * DPAD + d] = f2bf_bits((acc[nt][r] + bvv) * scale);
      }
    if (which == 0 && ob == 0){                      // zero Q pad d=48..63 (K pad harmless: Q pad=0)
      s16x8 z = {0,0,0,0,0,0,0,0};
      for (int i = threadIdx.x; i < 1024; i += 256){
        int n = nb + (i >> 4);
        int hh = (i >> 1) & 7;
        int dd = 48 + (i & 1) * 8;
        *(s16x8*)(QH + (((size_t)b * HEADS + hh) * N_PIX + n) * DPAD + dd) = z;
      }
    }
  }
}

// -------- Flash attention v2: KVBLK=128, XCD-swizzled grid, issue-early staging, defer-max --------
// S^T = mfma(K, Q): lane q=l16 holds S[q][j], j = ct*16 + lq*4 + r.  O^T = mfma(VT, P).
__global__ __launch_bounds__(256) void attn_kernel(const short* __restrict__ Q,
                                                   const short* __restrict__ K,
                                                   const short* __restrict__ VT,
                                                   short* __restrict__ AOUT){
  // XCD swizzle: f = (bh&7) + 8*((bh>>3)*36 + iblk)  ->  same-bh blocks share an XCD's L2
  int f = blockIdx.x;
  int t = f >> 3;
  int ib = (t % 36) * 64;
  int bh = (f & 7) + 8 * (t / 36);
  int b = bh >> 3, h = bh & 7;
  int tid = threadIdx.x;
  int wave = tid >> 6, lane = tid & 63;
  int l16 = lane & 15, lq = lane >> 4;
  int q0 = ib + wave * 16;

  __shared__ __align__(16) short kt[128 * 64];     // K tile [j][d], XOR-swizzled
  __shared__ __align__(16) short vt[64 * 128];     // V tile [d][j], XOR-swizzled
  __shared__ __align__(16) short pt[4][16 * 132];  // per-wave P [q][j-slot], padded row 132

  // staging geometry (constant per thread)
  int kr = tid >> 3, kc = tid & 7;                 // K rows kr+it*32, 16B chunk kc
  int ksw = (kc ^ (kr & 7)) * 8;
  int vr = tid >> 4, vc = tid & 15;                // V rows vr+it*16, 16B chunk vc
  int vsw = (vc ^ (vr & 7)) * 8;
  const short* kbase = K + (size_t)bh * N_PIX * DPAD;
  const short* vbase = VT + (size_t)bh * DPAD * N_PIX;

  Frag qf[2];
  {
    const short* qp = Q + ((size_t)bh * N_PIX + q0 + l16) * DPAD + lq * 8;
    qf[0].s = *(const s16x8*)(qp);
    qf[1].s = *(const s16x8*)(qp + 32);
  }

  Frag kst[4], vst[4];
  #pragma unroll
  for (int it = 0; it < 4; ++it){
    kst[it].s = *(const s16x8*)(kbase + (size_t)(kr + it * 32) * DPAD + kc * 8);
    vst[it].s = *(const s16x8*)(vbase + (size_t)(vr + it * 16) * N_PIX + vc * 8);
  }

  float m = -1e30f, l = 0.f;
  f32x4 oacc[3] = {};
  short* pw = &pt[wave][0];

  for (int jt = 0; jt < N_PIX / 128; ++jt){
    __syncthreads();                                // LDS free (prev compute done)
    #pragma unroll
    for (int it = 0; it < 4; ++it){
      *(s16x8*)(kt + (kr + it * 32) * 64 + ksw) = kst[it].s;
      *(s16x8*)(vt + (vr + it * 16) * 128 + vsw) = vst[it].s;
    }
    if (jt < N_PIX / 128 - 1){                      // issue next-tile loads: latency hides under MFMA
      const short* kb2 = kbase + (size_t)(jt + 1) * 128 * DPAD;
      const short* vb2 = vbase + (jt + 1) * 128;
      #pragma unroll
      for (int it = 0; it < 4; ++it){
        kst[it].s = *(const s16x8*)(kb2 + (size_t)(kr + it * 32) * DPAD + kc * 8);
        vst[it].s = *(const s16x8*)(vb2 + (size_t)(vr + it * 16) * N_PIX + vc * 8);
      }
    }
    __syncthreads();

    // S^T: 8 col-tiles of 16 j
    f32x4 sc[8];
    #pragma unroll
    for (int ct = 0; ct < 8; ++ct){
      sc[ct] = (f32x4){0.f, 0.f, 0.f, 0.f};
      int jr = ct * 16 + l16;
      #pragma unroll
      for (int kk = 0; kk < 2; ++kk){
        Frag kf;
        kf.s = *(const s16x8*)(kt + jr * 64 + ((kk * 4 + lq) ^ (jr & 7)) * 8);
        sc[ct] = __builtin_amdgcn_mfma_f32_16x16x32_bf16(kf.b, qf[kk].b, sc[ct], 0, 0, 0);
      }
    }

    // online softmax, lane-local (q=l16), defer-max: skip rescale while max growth <= 8 (exp2-dom)
    float mx = sc[0][0];
    #pragma unroll
    for (int ct = 0; ct < 8; ++ct)
      #pragma unroll
      for (int r = 0; r < 4; ++r) mx = fmaxf(mx, sc[ct][r]);
    mx = fmaxf(mx, __shfl_xor(mx, 16));
    mx = fmaxf(mx, __shfl_xor(mx, 32));
    if (!__all(mx <= m + 8.f)){
      float mnew = fmaxf(m, mx);
      float corr = __builtin_amdgcn_exp2f(m - mnew);
      m = mnew;
      l *= corr;
      #pragma unroll
      for (int dt = 0; dt < 3; ++dt)
        #pragma unroll
        for (int r = 0; r < 4; ++r) oacc[dt][r] *= corr;
    }
    float ps = 0.f;
    #pragma unroll
    for (int ct = 0; ct < 8; ++ct)
      #pragma unroll
      for (int r = 0; r < 4; ++r){
        float p = __builtin_amdgcn_exp2f(sc[ct][r] - m);
        sc[ct][r] = p; ps += p;
      }
    ps += __shfl_xor(ps, 16);
    ps += __shfl_xor(ps, 32);
    l += ps;

    // P -> per-wave LDS (padded rows: conflict-free): slot = (j>>2) ^ q
    #pragma unroll
    for (int ct = 0; ct < 8; ++ct){
      uint2 p; p.x = cvt_pk(sc[ct][0], sc[ct][1]); p.y = cvt_pk(sc[ct][2], sc[ct][3]);
      *(uint2*)(pw + l16 * 132 + (((ct * 4 + lq) ^ l16) * 4)) = p;
    }

    // O^T += VT * P^T
    #pragma unroll
    for (int kk = 0; kk < 4; ++kk){
      Frag pf;
      pf.u[0] = *(const uint2*)(pw + l16 * 132 + ((((kk * 8 + lq * 2)    ) ^ l16) * 4));
      pf.u[1] = *(const uint2*)(pw + l16 * 132 + ((((kk * 8 + lq * 2) + 1) ^ l16) * 4));
      #pragma unroll
      for (int dt = 0; dt < 3; ++dt){
        int vrr = dt * 16 + l16;
        Frag vf;
        vf.s = *(const s16x8*)(vt + vrr * 128 + ((kk * 4 + lq) ^ (vrr & 7)) * 8);
        oacc[dt] = __builtin_amdgcn_mfma_f32_16x16x32_bf16(vf.b, pf.b, oacc[dt], 0, 0, 0);
      }
    }
  }

  float inv = 1.f / l;
  short* op = AOUT + ((size_t)b * N_PIX + q0 + l16) * INNER + h * HDIM + lq * 4;
  #pragma unroll
  for (int dt = 0; dt < 3; ++dt){
    uint2 w;
    w.x = cvt_pk(oacc[dt][0] * inv, oacc[dt][1] * inv);
    w.y = cvt_pk(oacc[dt][2] * inv, oacc[dt][3] * inv);
    *(uint2*)(op + dt * 16) = w;
  }
}

// ---- Output projection + bias + residual: D[o][n]; both frags contiguous bf16 ----
__global__ __launch_bounds__(256) void proj_o(const short* __restrict__ WOB,
                                              const float* __restrict__ BO,
                                              const short* __restrict__ AOUT,
                                              const float* __restrict__ RES,
                                              float* __restrict__ OUT){
  int b = blockIdx.z, nb = blockIdx.x * 64, ob = blockIdx.y * 64;
  int wave = threadIdx.x >> 6, lane = threadIdx.x & 63;
  int l16 = lane & 15, lq = lane >> 4;
  int o0 = ob + wave * 16;

  f32x4 acc[4] = {};
  const short* abase = AOUT + ((size_t)b * N_PIX + nb) * INNER;
  #pragma unroll
  for (int k = 0; k < 12; ++k){
    Frag wf; wf.s = *(const s16x8*)(WOB + (size_t)(o0 + l16) * INNER + k * 32 + lq * 8);
    #pragma unroll
    for (int nt = 0; nt < 4; ++nt){
      Frag af; af.s = *(const s16x8*)(abase + (size_t)(nt * 16 + l16) * INNER + k * 32 + lq * 8);
      acc[nt] = __builtin_amdgcn_mfma_f32_16x16x32_bf16(wf.b, af.b, acc[nt], 0, 0, 0);
    }
  }
  #pragma unroll
  for (int r = 0; r < 4; ++r){
    int o = o0 + lq * 4 + r;
    float bv = BO[o];
    #pragma unroll
    for (int nt = 0; nt < 4; ++nt){
      int n = nb + nt * 16 + l16;
      size_t idx = ((size_t)b * C_IN + o) * N_PIX + n;
      OUT[idx] = acc[nt][r] + bv + RES[idx];
    }
  }
}

extern "C" void kernel_launch(void* const* d_in, const int* in_sizes, int n_in,
                              void* d_out, int out_size, void* d_ws, size_t ws_size,
                              hipStream_t stream){
  const float* q_feat = (const float*)d_in[0];
  const float* kv_feat= (const float*)d_in[1];
  const float* gn_w   = (const float*)d_in[2];
  const float* gn_b   = (const float*)d_in[3];
  const float* wq     = (const float*)d_in[4];
  const float* bq     = (const float*)d_in[5];
  const float* wk     = (const float*)d_in[6];
  const float* bk     = (const float*)d_in[7];
  const float* wv     = (const float*)d_in[8];
  const float* bv     = (const float*)d_in[9];
  const float* wo     = (const float*)d_in[10];
  const float* bo     = (const float*)d_in[11];
  float* out = (float*)d_out;

  char* ws = (char*)d_ws;
  float* mu = (float*)ws;
  float* rs = (float*)(ws + 512);
  short* wbf  = (short*)(ws + 4096);                    // 393216 shorts: wq|wk|wv|wo
  short* xtq  = (short*)(ws + 790528);                  // [b,n,256] bf16 (GN'd q)
  short* xtkv = (short*)(ws + 5509120);                 // [b,n,256] bf16
  short* qh   = (short*)(ws + 10227712);                // [b,h,n,64]
  short* kh   = (short*)(ws + 19664896);                // [b,h,n,64]
  short* vtb  = (short*)(ws + 29102080);                // [b,h,64,n]
  short* aout = (short*)(ws + 790528);                  // aliases xtq/xtkv (dead by attn)

  gn_wconv<<<320, 256, 0, stream>>>(q_feat, mu, rs, wq, wk, wv, wo, wbf);
  prep_x<<<dim3(36, 4, 8), 256, 0, stream>>>(q_feat, kv_feat, gn_w, gn_b, mu, rs, xtq, xtkv);
  proj_qkv<<<dim3(36, 18, 4), 256, 0, stream>>>(xtq, xtkv, wbf, bq, bk, bv, qh, kh, vtb);
  attn_kernel<<<1152, 256, 0, stream>>>(qh, kh, vtb, aout);
  proj_o<<<dim3(36, 4, 4), 256, 0, stream>>>(wbf + 294912, bo, aout, q_feat, out);
}

// Round 11
// 252.486 us; speedup vs baseline: 1.2509x; 1.2509x over previous
//
#include <hip/hip_runtime.h>
#include <hip/hip_bf16.h>

#define N_PIX 2304
#define C_IN  256
#define INNER 384
#define HEADS 8
#define HDIM  48
#define DPAD  64
// attention scale folded with log2(e): softmax runs in exp2 domain
#define QSCALE (0.14433756729740643f * 1.44269504088896341f)

typedef __bf16 bf16x8 __attribute__((ext_vector_type(8)));
typedef float  f32x4  __attribute__((ext_vector_type(4)));
typedef short  s16x8  __attribute__((ext_vector_type(8)));

union Frag { s16x8 s; bf16x8 b; uint2 u[2]; };

__device__ inline short f2bf_bits(float f){
  union { float f; unsigned u; } v; v.f = f;
  unsigned r = v.u + 0x7fffu + ((v.u >> 16) & 1u);
  return (short)(r >> 16);
}

__device__ inline unsigned cvt_pk(float a, float b){
  unsigned r; asm("v_cvt_pk_bf16_f32 %0, %1, %2" : "=v"(r) : "v"(a), "v"(b));
  return r;
}

// ---------------- GroupNorm stats: one block per (b,g) ----------------
__global__ __launch_bounds__(256) void gn_stats(const float* __restrict__ x,
                                                float* __restrict__ mu,
                                                float* __restrict__ rs){
  int bg = blockIdx.x;
  const float* p = x + (size_t)bg * 8 * N_PIX;
  float s = 0.f, s2 = 0.f;
  for (int i = threadIdx.x; i < 8 * N_PIX; i += 256){
    float v = p[i]; s += v; s2 += v * v;
  }
  __shared__ float ls[256], ls2[256];
  ls[threadIdx.x] = s; ls2[threadIdx.x] = s2;
  __syncthreads();
  for (int off = 128; off > 0; off >>= 1){
    if ((int)threadIdx.x < off){ ls[threadIdx.x] += ls[threadIdx.x + off]; ls2[threadIdx.x] += ls2[threadIdx.x + off]; }
    __syncthreads();
  }
  if (threadIdx.x == 0){
    float m = ls[0] / 18432.f;
    float var = ls2[0] / 18432.f - m * m;
    mu[bg] = m; rs[bg] = rsqrtf(var + 1e-5f);
  }
}

// ---- fused prep+projection: stage GN'd/raw X tile [64n][256c] bf16 in LDS once,
//      then 6 o-tiles of MFMA with W converted f32->bf16 inline.
//      role y: 0 = Q (GN, scale, pad-zero), 1 = K, 2 = V (transposed output) ----
__global__ __launch_bounds__(256) void proj_fused(const float* __restrict__ Xq,
                                                  const float* __restrict__ Xkv,
                                                  const float* __restrict__ gnw,
                                                  const float* __restrict__ gnb,
                                                  const float* __restrict__ mu,
                                                  const float* __restrict__ rs,
                                                  const float* __restrict__ WQ,
                                                  const float* __restrict__ WK,
                                                  const float* __restrict__ WV,
                                                  const float* __restrict__ bq,
                                                  const float* __restrict__ bk,
                                                  const float* __restrict__ bv,
                                                  short* __restrict__ QH,
                                                  short* __restrict__ KH,
                                                  short* __restrict__ VTB){
  int b = blockIdx.z, nb = blockIdx.x * 64;
  int role = blockIdx.y;                       // 0=Q 1=K 2=V
  const float* X = role ? Xkv : Xq;
  const float* W = (role == 0) ? WQ : (role == 1 ? WK : WV);
  const float* bias = (role == 0) ? bq : (role == 1 ? bk : bv);

  __shared__ __align__(16) short lt[64][68];   // transpose staging slice
  __shared__ __align__(16) short xt[64 * 256]; // [n][c] bf16, 16B-chunk XOR swizzle

  int t = threadIdx.x;
  // ---- build xt: 4 slices of 64 channels ----
  int c_l = t >> 4, n4 = (t & 15) * 4;
  for (int cs = 0; cs < 4; ++cs){
    #pragma unroll
    for (int i = 0; i < 4; ++i){
      int cl = c_l + i * 16, c = cs * 64 + cl;
      float4 v = *(const float4*)(X + ((size_t)b * C_IN + c) * N_PIX + nb + n4);
      if (role == 0){
        int bg = b * 32 + (c >> 3);
        float w = gnw[c] * rs[bg], bb = gnb[c] - mu[bg] * w;
        v.x = v.x * w + bb; v.y = v.y * w + bb; v.z = v.z * w + bb; v.w = v.w * w + bb;
      }
      uint2 p; p.x = cvt_pk(v.x, v.y); p.y = cvt_pk(v.z, v.w);
      *(uint2*)&lt[cl][n4] = p;
    }
    __syncthreads();
    #pragma unroll
    for (int i = 0; i < 2; ++i){
      int idx = t + i * 256;
      int n = idx >> 3, c8 = idx & 7;
      s16x8 o;
      #pragma unroll
      for (int j = 0; j < 8; ++j) o[j] = lt[c8 * 8 + j][n];
      int gc = cs * 8 + c8;                     // global 16B chunk 0..31
      *(s16x8*)(xt + n * 256 + ((gc ^ (n & 7)) * 8)) = o;
    }
    __syncthreads();
  }

  int wave = t >> 6, lane = t & 63;
  int l16 = lane & 15, lq = lane >> 4;

  for (int ob = 0; ob < 6; ++ob){
    int o0 = ob * 64 + wave * 16;
    f32x4 acc[4] = {};
    #pragma unroll
    for (int k = 0; k < 8; ++k){
      const float* wp = W + (size_t)(o0 + l16) * C_IN + k * 32 + lq * 8;
      float4 w0 = *(const float4*)wp;
      float4 w1 = *(const float4*)(wp + 4);
      Frag wf;
      wf.u[0].x = cvt_pk(w0.x, w0.y); wf.u[0].y = cvt_pk(w0.z, w0.w);
      wf.u[1].x = cvt_pk(w1.x, w1.y); wf.u[1].y = cvt_pk(w1.z, w1.w);
      #pragma unroll
      for (int nt = 0; nt < 4; ++nt){
        int row = nt * 16 + l16;
        Frag af; af.s = *(const s16x8*)(xt + row * 256 + (((k * 4 + lq) ^ (row & 7)) * 8));
        acc[nt] = (role == 2)
          ? __builtin_amdgcn_mfma_f32_16x16x32_bf16(wf.b, af.b, acc[nt], 0, 0, 0)   // D[o][n]
          : __builtin_amdgcn_mfma_f32_16x16x32_bf16(af.b, wf.b, acc[nt], 0, 0, 0);  // D[n][o]
      }
    }
    if (role == 2){                              // V -> VT[b,h,d,n]
      #pragma unroll
      for (int r = 0; r < 4; ++r){
        int o = o0 + lq * 4 + r;
        int h = (o * 683) >> 15, d = o - h * 48;
        float bvv = bias[o];
        #pragma unroll
        for (int nt = 0; nt < 4; ++nt){
          int n = nb + nt * 16 + l16;
          VTB[(((size_t)b * HEADS + h) * DPAD + d) * N_PIX + n] = f2bf_bits(acc[nt][r] + bvv);
        }
      }
    } else {                                     // Q/K -> [b,h,n,64]
      short* OUT = role ? KH : QH;
      float scale = role ? 1.0f : (float)QSCALE;
      int o = o0 + l16;
      int h = (o * 683) >> 15, d = o - h * 48;
      float bvv = bias[o];
      #pragma unroll
      for (int nt = 0; nt < 4; ++nt)
        #pragma unroll
        for (int r = 0; r < 4; ++r){
          int n = nb + nt * 16 + lq * 4 + r;
          OUT[(((size_t)b * HEADS + h) * N_PIX + n) * DPAD + d] = f2bf_bits((acc[nt][r] + bvv) * scale);
        }
    }
  }

  if (role == 0){                                // zero Q pad d=48..63 (K pad x Qpad0 = 0)
    s16x8 z = {0,0,0,0,0,0,0,0};
    for (int i = t; i < 1024; i += 256){
      int n = nb + (i >> 4);
      int hh = (i >> 1) & 7;
      int dd = 48 + (i & 1) * 8;
      *(s16x8*)(QH + (((size_t)b * HEADS + hh) * N_PIX + n) * DPAD + dd) = z;
    }
  }
}

// -------- Flash attention v3: KVBLK=64 (R7 conflict-cheap layouts), QBLK=32/wave,
//          XCD-swizzled grid, issue-early reg staging, defer-max --------
__global__ __launch_bounds__(256) void attn_kernel(const short* __restrict__ Q,
                                                   const short* __restrict__ K,
                                                   const short* __restrict__ VT,
                                                   short* __restrict__ AOUT){
  // 576 blocks: same-XCD blocks share 4 bh values -> K/V L2-resident
  int f = blockIdx.x;
  int t = f >> 3;
  int ib = (t % 18) * 128;
  int bh = (f & 7) + 8 * (t / 18);
  int b = bh >> 3, h = bh & 7;
  int tid = threadIdx.x;
  int wave = tid >> 6, lane = tid & 63;
  int l16 = lane & 15, lq = lane >> 4;
  int q0 = ib + wave * 32;

  __shared__ __align__(16) short kt[64 * 64];      // K tile [j][d], XOR-swizzled (R7)
  __shared__ __align__(16) short vt[64 * 64];      // V tile [d][j], XOR-swizzled (R7)
  __shared__ __align__(16) short pt[4][32 * 64];   // per-wave P [q][j-slot] (R7 slot swizzle)

  int srow = tid >> 3, scb = tid & 7;              // staging: rows srow+it*32, chunk scb
  int ssw = (scb ^ (srow & 7)) * 8;
  const short* kbase = K + (size_t)bh * N_PIX * DPAD;
  const short* vbase = VT + (size_t)bh * DPAD * N_PIX;

  Frag qf[2][2];
  #pragma unroll
  for (int s = 0; s < 2; ++s){
    const short* qp = Q + ((size_t)bh * N_PIX + q0 + s * 16 + l16) * DPAD + lq * 8;
    qf[s][0].s = *(const s16x8*)(qp);
    qf[s][1].s = *(const s16x8*)(qp + 32);
  }

  Frag kst[2], vst[2];
  #pragma unroll
  for (int it = 0; it < 2; ++it){
    kst[it].s = *(const s16x8*)(kbase + (size_t)(srow + it * 32) * DPAD + scb * 8);
    vst[it].s = *(const s16x8*)(vbase + (size_t)(srow + it * 32) * N_PIX + scb * 8);
  }

  float m[2] = {-1e30f, -1e30f}, l[2] = {0.f, 0.f};
  f32x4 oacc[2][3] = {};
  short* pw = &pt[wave][0];

  for (int jt = 0; jt < N_PIX / 64; ++jt){
    __syncthreads();
    #pragma unroll
    for (int it = 0; it < 2; ++it){
      *(s16x8*)(kt + (srow + it * 32) * 64 + ssw) = kst[it].s;
      *(s16x8*)(vt + (srow + it * 32) * 64 + ssw) = vst[it].s;
    }
    if (jt < N_PIX / 64 - 1){                     // issue next-tile loads early
      const short* kb2 = kbase + (size_t)(jt + 1) * 64 * DPAD;
      const short* vb2 = vbase + (jt + 1) * 64;
      #pragma unroll
      for (int it = 0; it < 2; ++it){
        kst[it].s = *(const s16x8*)(kb2 + (size_t)(srow + it * 32) * DPAD + scb * 8);
        vst[it].s = *(const s16x8*)(vb2 + (size_t)(srow + it * 32) * N_PIX + scb * 8);
      }
    }
    __syncthreads();

    // per q-subtile: S^T -> softmax -> P store
    #pragma unroll
    for (int s = 0; s < 2; ++s){
      f32x4 sc[4];
      #pragma unroll
      for (int ct = 0; ct < 4; ++ct){
        sc[ct] = (f32x4){0.f, 0.f, 0.f, 0.f};
        int jr = ct * 16 + l16;
        #pragma unroll
        for (int kk = 0; kk < 2; ++kk){
          Frag kf;
          kf.s = *(const s16x8*)(kt + jr * 64 + ((kk * 4 + lq) ^ (jr & 7)) * 8);
          sc[ct] = __builtin_amdgcn_mfma_f32_16x16x32_bf16(kf.b, qf[s][kk].b, sc[ct], 0, 0, 0);
        }
      }
      float mx = sc[0][0];
      #pragma unroll
      for (int ct = 0; ct < 4; ++ct)
        #pragma unroll
        for (int r = 0; r < 4; ++r) mx = fmaxf(mx, sc[ct][r]);
      mx = fmaxf(mx, __shfl_xor(mx, 16));
      mx = fmaxf(mx, __shfl_xor(mx, 32));
      if (!__all(mx <= m[s] + 8.f)){              // defer-max: skip rescale for small growth
        float mn = fmaxf(m[s], mx);
        float corr = __builtin_amdgcn_exp2f(m[s] - mn);
        m[s] = mn; l[s] *= corr;
        #pragma unroll
        for (int dt = 0; dt < 3; ++dt)
          #pragma unroll
          for (int r = 0; r < 4; ++r) oacc[s][dt][r] *= corr;
      }
      float ps = 0.f;
      #pragma unroll
      for (int ct = 0; ct < 4; ++ct)
        #pragma unroll
        for (int r = 0; r < 4; ++r){
          float p = __builtin_amdgcn_exp2f(sc[ct][r] - m[s]);
          sc[ct][r] = p; ps += p;
        }
      ps += __shfl_xor(ps, 16);
      ps += __shfl_xor(ps, 32);
      l[s] += ps;
      #pragma unroll
      for (int ct = 0; ct < 4; ++ct){
        uint2 p; p.x = cvt_pk(sc[ct][0], sc[ct][1]); p.y = cvt_pk(sc[ct][2], sc[ct][3]);
        *(uint2*)(pw + (s * 16 + l16) * 64 + (((ct * 4 + lq) ^ l16) * 4)) = p;
      }
    }

    // O^T += VT * P^T   (vf shared across both q-subtiles)
    #pragma unroll
    for (int kk = 0; kk < 2; ++kk){
      Frag vf[3];
      #pragma unroll
      for (int dt = 0; dt < 3; ++dt){
        int vr = dt * 16 + l16;
        vf[dt].s = *(const s16x8*)(vt + vr * 64 + ((kk * 4 + lq) ^ (vr & 7)) * 8);
      }
      #pragma unroll
      for (int s = 0; s < 2; ++s){
        Frag pf;
        pf.u[0] = *(const uint2*)(pw + (s * 16 + l16) * 64 + ((((kk * 8 + lq * 2)    ) ^ l16) * 4));
        pf.u[1] = *(const uint2*)(pw + (s * 16 + l16) * 64 + ((((kk * 8 + lq * 2) + 1) ^ l16) * 4));
        #pragma unroll
        for (int dt = 0; dt < 3; ++dt)
          oacc[s][dt] = __builtin_amdgcn_mfma_f32_16x16x32_bf16(vf[dt].b, pf.b, oacc[s][dt], 0, 0, 0);
      }
    }
  }

  #pragma unroll
  for (int s = 0; s < 2; ++s){
    float inv = 1.f / l[s];
    short* op = AOUT + ((size_t)b * N_PIX + q0 + s * 16 + l16) * INNER + h * HDIM + lq * 4;
    #pragma unroll
    for (int dt = 0; dt < 3; ++dt){
      uint2 w;
      w.x = cvt_pk(oacc[s][dt][0] * inv, oacc[s][dt][1] * inv);
      w.y = cvt_pk(oacc[s][dt][2] * inv, oacc[s][dt][3] * inv);
      *(uint2*)(op + dt * 16) = w;
    }
  }
}

// ---- Output projection + bias + residual: D[o][n]; wo converted inline ----
__global__ __launch_bounds__(256) void proj_o(const float* __restrict__ WO,
                                              const float* __restrict__ BO,
                                              const short* __restrict__ AOUT,
                                              const float* __restrict__ RES,
                                              float* __restrict__ OUT){
  int b = blockIdx.z, nb = blockIdx.x * 64, ob = blockIdx.y * 64;
  int wave = threadIdx.x >> 6, lane = threadIdx.x & 63;
  int l16 = lane & 15, lq = lane >> 4;
  int o0 = ob + wave * 16;

  f32x4 acc[4] = {};
  const short* abase = AOUT + ((size_t)b * N_PIX + nb) * INNER;
  #pragma unroll
  for (int k = 0; k < 12; ++k){
    const float* wp = WO + (size_t)(o0 + l16) * INNER + k * 32 + lq * 8;
    float4 w0 = *(const float4*)wp;
    float4 w1 = *(const float4*)(wp + 4);
    Frag wf;
    wf.u[0].x = cvt_pk(w0.x, w0.y); wf.u[0].y = cvt_pk(w0.z, w0.w);
    wf.u[1].x = cvt_pk(w1.x, w1.y); wf.u[1].y = cvt_pk(w1.z, w1.w);
    #pragma unroll
    for (int nt = 0; nt < 4; ++nt){
      Frag af; af.s = *(const s16x8*)(abase + (size_t)(nt * 16 + l16) * INNER + k * 32 + lq * 8);
      acc[nt] = __builtin_amdgcn_mfma_f32_16x16x32_bf16(wf.b, af.b, acc[nt], 0, 0, 0);
    }
  }
  #pragma unroll
  for (int r = 0; r < 4; ++r){
    int o = o0 + lq * 4 + r;
    float bv = BO[o];
    #pragma unroll
    for (int nt = 0; nt < 4; ++nt){
      int n = nb + nt * 16 + l16;
      size_t idx = ((size_t)b * C_IN + o) * N_PIX + n;
      OUT[idx] = acc[nt][r] + bv + RES[idx];
    }
  }
}

extern "C" void kernel_launch(void* const* d_in, const int* in_sizes, int n_in,
                              void* d_out, int out_size, void* d_ws, size_t ws_size,
                              hipStream_t stream){
  const float* q_feat = (const float*)d_in[0];
  const float* kv_feat= (const float*)d_in[1];
  const float* gn_w   = (const float*)d_in[2];
  const float* gn_b   = (const float*)d_in[3];
  const float* wq     = (const float*)d_in[4];
  const float* bq     = (const float*)d_in[5];
  const float* wk     = (const float*)d_in[6];
  const float* bk     = (const float*)d_in[7];
  const float* wv     = (const float*)d_in[8];
  const float* bv     = (const float*)d_in[9];
  const float* wo     = (const float*)d_in[10];
  const float* bo     = (const float*)d_in[11];
  float* out = (float*)d_out;

  char* ws = (char*)d_ws;
  float* mu = (float*)ws;
  float* rs = (float*)(ws + 512);
  const size_t HSZ = (size_t)32 * N_PIX * DPAD * sizeof(short);   // 9.44 MB
  short* qh   = (short*)(ws + 4096);
  short* kh   = (short*)(ws + 4096 + HSZ);
  short* vtb  = (short*)(ws + 4096 + 2 * HSZ);
  short* aout = (short*)(ws + 4096 + 3 * HSZ);                    // [b,n,384] bf16

  gn_stats<<<128, 256, 0, stream>>>(q_feat, mu, rs);
  proj_fused<<<dim3(36, 3, 4), 256, 0, stream>>>(q_feat, kv_feat, gn_w, gn_b, mu, rs,
                                                 wq, wk, wv, bq, bk, bv, qh, kh, vtb);
  attn_kernel<<<576, 256, 0, stream>>>(qh, kh, vtb, aout);
  proj_o<<<dim3(36, 4, 4), 256, 0, stream>>>(wo, bo, aout, q_feat, out);
}